// Round 15
// baseline (1714.651 us; speedup 1.0000x reference)
//
#include <hip/hip_runtime.h>
#include <hip/hip_bf16.h>
#include <math.h>

#define BB 8
#define SS 512
#define DD 1024
#define LL 6
#define HH 8
#define HDD 128
#define FFF 4096
#define EPSF 1e-5f
#define SCALEF 0.08838834764831845f  // 1/sqrt(128)

typedef __attribute__((ext_vector_type(8))) _Float16 f16x8;
typedef __attribute__((ext_vector_type(4))) _Float16 f16x4;
typedef __attribute__((ext_vector_type(4))) float f32x4;

__device__ __forceinline__ void gload16(const void* g, void* l) {
  __builtin_amdgcn_global_load_lds(
      (const __attribute__((address_space(1))) void*)g,
      (__attribute__((address_space(3))) void*)l, 16, 0, 0);
}

// ===========================================================================
// gemmk: m97 structure, R11/R14-proven config (UNCHANGED from R14).
// ===========================================================================
__global__ __launch_bounds__(256, 3) void gemmk_kernel(
    const _Float16* __restrict__ Ag, const _Float16* __restrict__ Bg,
    const float* __restrict__ bias, void* __restrict__ outp,
    int Ndim, int Kdim, int Kstr, long zsA, long zsB, long zsOut, int emode,
    int ktail64, int nzlast) {
  __shared__ _Float16 lA[8192];  // 16KB: 128 rows x 64 halves (128B rows)
  __shared__ _Float16 lB[8192];
  const int tid = threadIdx.x;
  const int lane = tid & 63;
  const int wid = tid >> 6;
  const int z = blockIdx.z;
  const int m0 = blockIdx.y * 128;
  const int n0 = blockIdx.x * 128;
  const long K2 = (long)Kstr * 2;
  const char* Azc = (const char*)(Ag + (long)z * zsA + (long)m0 * Kstr);
  const char* Bzc = (const char*)(Bg + (long)z * zsB + (long)n0 * Kstr);

  const int wm = (wid >> 1) * 64;
  const int wn = (wid & 1) * 64;
  const int r16 = lane & 15;
  const int kq = lane >> 4;  // 16B slot 0..3

  long roff[4];  // shared A/B staging geometry: row r, swizzled col sc
#pragma unroll
  for (int i = 0; i < 4; ++i) {
    const int idx = tid + i * 256;
    const int r = idx >> 3;
    const int sc = ((idx & 7) << 4) ^ ((r & 7) << 4);
    roff[i] = (long)r * K2 + sc;
  }

  f32x4 acc[4][4];
#pragma unroll
  for (int mi = 0; mi < 4; ++mi)
#pragma unroll
    for (int ni = 0; ni < 4; ++ni) acc[mi][ni] = (f32x4){0.f, 0.f, 0.f, 0.f};

  const int nt = (Kdim >> 6) + ((z == nzlast) ? ktail64 : 0);
  for (int t = 0; t < nt; ++t) {
    const int kb = t << 7;  // 128B per K-step
    __syncthreads();
#pragma unroll
    for (int i = 0; i < 4; ++i) {
      gload16(Azc + roff[i] + kb, (char*)lA + tid * 16 + i * 4096);
      gload16(Bzc + roff[i] + kb, (char*)lB + tid * 16 + i * 4096);
    }
    __syncthreads();
#pragma unroll
    for (int kk = 0; kk < 2; ++kk) {
      f16x8 af[4], bf[4];
#pragma unroll
      for (int mi = 0; mi < 4; ++mi) {
        const int R = wm + mi * 16 + r16;
        af[mi] = *(const f16x8*)((const char*)lA + R * 128 +
                                 ((kk * 64 + kq * 16) ^ ((R & 7) << 4)));
      }
#pragma unroll
      for (int ni = 0; ni < 4; ++ni) {
        const int R = wn + ni * 16 + r16;
        bf[ni] = *(const f16x8*)((const char*)lB + R * 128 +
                                 ((kk * 64 + kq * 16) ^ ((R & 7) << 4)));
      }
#pragma unroll
      for (int mi = 0; mi < 4; ++mi)
#pragma unroll
        for (int ni = 0; ni < 4; ++ni)
          acc[mi][ni] = __builtin_amdgcn_mfma_f32_16x16x32_f16(
              af[mi], bf[ni], acc[mi][ni], 0, 0, 0);
    }
  }

  _Float16* outH = (_Float16*)outp + (long)z * zsOut;
  const int rj = (lane >> 4) << 2;
  const long MSZq = (long)BB * SS * DD;
#pragma unroll
  for (int mi = 0; mi < 4; ++mi) {
#pragma unroll
    for (int ni = 0; ni < 4; ++ni) {
      const int col = n0 + wn + ni * 16 + r16;
#pragma unroll
      for (int j = 0; j < 4; ++j) {
        const int row = m0 + wm + mi * 16 + rj + j;
        float vv = acc[mi][ni][j];
        if (emode == 1) {  // fused qkv scatter; V written transposed
          vv += bias[col];
          int wsel = col >> 10, c = col & 1023;
          int b_ = row >> 9, s_ = row & 511;
          int hh = c >> 7, hd_ = c & 127;
          if (wsel < 2) {
            outH[wsel * MSZq + (((long)(b_ * HH + hh)) * SS + s_) * HDD + hd_] =
                (_Float16)vv;
          } else {  // V -> [B*H][HD][S]
            outH[2 * MSZq + (((long)(b_ * HH + hh)) * HDD + hd_) * SS + s_] =
                (_Float16)vv;
          }
        } else if (emode == 5) {  // exact GELU(bias+acc), f16
          vv += bias[col];
          vv = 0.5f * vv * (1.0f + erff(vv * 0.70710678118654752f));
          outH[(long)row * Ndim + col] = (_Float16)vv;
        } else {  // 6: f16 split-K partial
          outH[(long)row * Ndim + col] = (_Float16)vv;
        }
      }
    }
  }
}

// ===========================================================================
// flash: fused QK^T + online softmax + PV. NOW 8 waves x 16-q strips per
// 128-q block (512 threads); grid unchanged (4,64)=256 blocks -> 2 waves/SIMD
// (was 1): softmax VALU of one wave overlaps MFMA of its SIMD partner.
// Wave body = R10's 16q version (correctness-proven). PV swapped
// (out^T = mfma(V^T-rows, P-as-B)); rescale/1-over-l per-lane.
// ===========================================================================
__global__ __launch_bounds__(512) void flash_kernel(
    const _Float16* __restrict__ Qg, const _Float16* __restrict__ Kg,
    const _Float16* __restrict__ Vt, const int* __restrict__ amask,
    _Float16* __restrict__ xout) {
  __shared__ _Float16 Pl[8][16][136];
  __shared__ float rf_s[8][16];
  const int tid = threadIdx.x;
  const int lane = tid & 63;
  const int w = tid >> 6;  // 0..7
  const int bh = blockIdx.y;
  const int b_ = bh >> 3, hh = bh & 7;
  const int q0 = blockIdx.x * 128 + w * 16;
  const int r16 = lane & 15;
  const int kq = lane >> 4;
  const int rj = kq << 2;
  const _Float16* Qb = Qg + ((long)bh * SS + q0) * HDD;
  const _Float16* Kb = Kg + (long)bh * SS * HDD;
  const _Float16* Vb = Vt + (long)bh * HDD * SS;

  f16x8 qa[4];
#pragma unroll
  for (int kk = 0; kk < 4; ++kk)
    qa[kk] = *(const f16x8*)(Qb + (long)r16 * HDD + kk * 32 + kq * 8);

  f32x4 acc[8];  // out^T: [hd 8x16][q 16]
#pragma unroll
  for (int mi = 0; mi < 8; ++mi) acc[mi] = (f32x4){0.f, 0.f, 0.f, 0.f};
  float mrun[4], lrun[4];
#pragma unroll
  for (int j = 0; j < 4; ++j) {
    mrun[j] = -INFINITY;
    lrun[j] = 0.f;
  }

  for (int kt = 0; kt < 4; ++kt) {
    __syncthreads();  // protect Pl/rf_s reuse
    const int s0 = kt * 128;
    int am[8];
#pragma unroll
    for (int ni = 0; ni < 8; ++ni)
      am[ni] = amask[b_ * SS + s0 + ni * 16 + r16];

    f32x4 sc[8];
#pragma unroll
    for (int ni = 0; ni < 8; ++ni) sc[ni] = (f32x4){0.f, 0.f, 0.f, 0.f};
#pragma unroll
    for (int ni = 0; ni < 8; ++ni) {
      f16x8 kf[4];
#pragma unroll
      for (int kk = 0; kk < 4; ++kk)
        kf[kk] = *(const f16x8*)(Kb + (long)(s0 + ni * 16 + r16) * HDD +
                                 kk * 32 + kq * 8);
#pragma unroll
      for (int kk = 0; kk < 4; ++kk)
        sc[ni] = __builtin_amdgcn_mfma_f32_16x16x32_f16(qa[kk], kf[kk], sc[ni],
                                                        0, 0, 0);
    }
#pragma unroll
    for (int ni = 0; ni < 8; ++ni)
#pragma unroll
      for (int j = 0; j < 4; ++j)
        sc[ni][j] = am[ni] ? sc[ni][j] * SCALEF : -10000.0f;

    float rf[4];
#pragma unroll
    for (int j = 0; j < 4; ++j) {
      float rm = -INFINITY;
#pragma unroll
      for (int ni = 0; ni < 8; ++ni) rm = fmaxf(rm, sc[ni][j]);
#pragma unroll
      for (int off = 1; off < 16; off <<= 1) rm = fmaxf(rm, __shfl_xor(rm, off));
      const float mn = fmaxf(mrun[j], rm);
      const float rfv = __expf(mrun[j] - mn);
      mrun[j] = mn;
      float rs = 0.f;
#pragma unroll
      for (int ni = 0; ni < 8; ++ni) {
        const float p = __expf(sc[ni][j] - mn);
        sc[ni][j] = p;
        rs += p;
      }
#pragma unroll
      for (int off = 1; off < 16; off <<= 1) rs += __shfl_xor(rs, off);
      lrun[j] = lrun[j] * rfv + rs;
      rf[j] = rfv;
    }
    if (r16 == 0) {
#pragma unroll
      for (int j = 0; j < 4; ++j) rf_s[w][rj + j] = rf[j];
    }
#pragma unroll
    for (int ni = 0; ni < 8; ++ni)
#pragma unroll
      for (int j = 0; j < 4; ++j)
        Pl[w][rj + j][ni * 16 + r16] = (_Float16)sc[ni][j];
    __syncthreads();

    const float rfq = rf_s[w][r16];
#pragma unroll
    for (int mi = 0; mi < 8; ++mi)
#pragma unroll
      for (int j = 0; j < 4; ++j) acc[mi][j] *= rfq;

    f16x8 pb[4];
#pragma unroll
    for (int kk = 0; kk < 4; ++kk)
      pb[kk] = *(const f16x8*)(&Pl[w][r16][kk * 32 + kq * 8]);
#pragma unroll
    for (int mi = 0; mi < 8; ++mi) {
      f16x8 va[4];
#pragma unroll
      for (int kk = 0; kk < 4; ++kk)
        va[kk] = *(const f16x8*)(Vb + (long)(mi * 16 + r16) * SS + s0 +
                                 kk * 32 + kq * 8);
#pragma unroll
      for (int kk = 0; kk < 4; ++kk)
        acc[mi] = __builtin_amdgcn_mfma_f32_16x16x32_f16(va[kk], pb[kk],
                                                         acc[mi], 0, 0, 0);
    }
  }

  __syncthreads();
  if (r16 == 0) {
#pragma unroll
    for (int j = 0; j < 4; ++j) rf_s[w][rj + j] = 1.0f / lrun[j];
  }
  __syncthreads();
  const float lq = rf_s[w][r16];
#pragma unroll
  for (int mi = 0; mi < 8; ++mi) {
    f16x4 o;
#pragma unroll
    for (int j = 0; j < 4; ++j) o[j] = (_Float16)(acc[mi][j] * lq);
    *(f16x4*)(&xout[((long)(b_ * SS + q0 + r16)) * DD + hh * HDD + mi * 16 +
                    rj]) = o;
  }
}

// ===========================================================================
// reduce_ln: h[row] = (res?res:0) + bias + sum parts; optional LN -> x (f16)
// ===========================================================================
__global__ __launch_bounds__(256) void reduce_ln_kernel(
    const _Float16* __restrict__ parts, int npart,
    const float* __restrict__ res, const float* __restrict__ bias,
    const float* __restrict__ lg, const float* __restrict__ lb,
    float* __restrict__ hout, _Float16* __restrict__ xout, long pzs) {
  const int row = blockIdx.x;
  const int c = threadIdx.x << 2;
  const long base = (long)row * DD + c;
  float4 a = *reinterpret_cast<const float4*>(&bias[c]);
  if (res) {
    const float4 r = *reinterpret_cast<const float4*>(&res[base]);
    a.x += r.x; a.y += r.y; a.z += r.z; a.w += r.w;
  }
  for (int p = 0; p < npart; ++p) {
    const f16x4 hpv = *reinterpret_cast<const f16x4*>(&parts[p * pzs + base]);
    a.x += (float)hpv[0]; a.y += (float)hpv[1];
    a.z += (float)hpv[2]; a.w += (float)hpv[3];
  }
  *reinterpret_cast<float4*>(&hout[base]) = a;
  if (!lg) return;
  float s = a.x + a.y + a.z + a.w;
  float ss = a.x * a.x + a.y * a.y + a.z * a.z + a.w * a.w;
#pragma unroll
  for (int off = 32; off; off >>= 1) {
    s += __shfl_down(s, off);
    ss += __shfl_down(ss, off);
  }
  __shared__ float red[8];
  const int wid = threadIdx.x >> 6, lane = threadIdx.x & 63;
  if (lane == 0) { red[wid] = s; red[4 + wid] = ss; }
  __syncthreads();
  if (threadIdx.x == 0) {
    s = red[0] + red[1] + red[2] + red[3];
    ss = red[4] + red[5] + red[6] + red[7];
    float mean = s * (1.0f / DD);
    float var = ss * (1.0f / DD) - mean * mean;
    red[0] = mean;
    red[1] = rsqrtf(var + EPSF);
  }
  __syncthreads();
  const float mean = red[0], rstd = red[1];
  const float4 gv = *reinterpret_cast<const float4*>(&lg[c]);
  const float4 bv = *reinterpret_cast<const float4*>(&lb[c]);
  f16x4 o;
  o[0] = (_Float16)((a.x - mean) * rstd * gv.x + bv.x);
  o[1] = (_Float16)((a.y - mean) * rstd * gv.y + bv.y);
  o[2] = (_Float16)((a.z - mean) * rstd * gv.z + bv.z);
  o[3] = (_Float16)((a.w - mean) * rstd * gv.w + bv.w);
  *reinterpret_cast<f16x4*>(&xout[base]) = o;
}

// embed + layer-0 ln1 fused
__global__ __launch_bounds__(256) void embed_ln_kernel(
    const int* __restrict__ ids, const int* __restrict__ curpos,
    const float* __restrict__ tok, const float* __restrict__ pos,
    const float* __restrict__ lg, const float* __restrict__ lb,
    float* __restrict__ h, _Float16* __restrict__ x) {
  const int rs = blockIdx.x;
  const int s_ = rs & (SS - 1);
  const int t = ids[rs];
  const int p = curpos[0] + s_;
  const int c = threadIdx.x << 2;
  const float4 tv = *reinterpret_cast<const float4*>(&tok[(long)t * DD + c]);
  const float4 pv = *reinterpret_cast<const float4*>(&pos[(long)p * DD + c]);
  float4 a = {tv.x + pv.x, tv.y + pv.y, tv.z + pv.z, tv.w + pv.w};
  *reinterpret_cast<float4*>(&h[(long)rs * DD + c]) = a;
  float s = a.x + a.y + a.z + a.w;
  float ss = a.x * a.x + a.y * a.y + a.z * a.z + a.w * a.w;
#pragma unroll
  for (int off = 32; off; off >>= 1) {
    s += __shfl_down(s, off);
    ss += __shfl_down(ss, off);
  }
  __shared__ float red[8];
  const int wid = threadIdx.x >> 6, lane = threadIdx.x & 63;
  if (lane == 0) { red[wid] = s; red[4 + wid] = ss; }
  __syncthreads();
  if (threadIdx.x == 0) {
    s = red[0] + red[1] + red[2] + red[3];
    ss = red[4] + red[5] + red[6] + red[7];
    float mean = s * (1.0f / DD);
    float var = ss * (1.0f / DD) - mean * mean;
    red[0] = mean;
    red[1] = rsqrtf(var + EPSF);
  }
  __syncthreads();
  const float mean = red[0], rstd = red[1];
  const float4 gv = *reinterpret_cast<const float4*>(&lg[c]);
  const float4 bv = *reinterpret_cast<const float4*>(&lb[c]);
  f16x4 o;
  o[0] = (_Float16)((a.x - mean) * rstd * gv.x + bv.x);
  o[1] = (_Float16)((a.y - mean) * rstd * gv.y + bv.y);
  o[2] = (_Float16)((a.z - mean) * rstd * gv.z + bv.z);
  o[3] = (_Float16)((a.w - mean) * rstd * gv.w + bv.w);
  *reinterpret_cast<f16x4*>(&x[(long)rs * DD + c]) = o;
}

// per-layer slab (f16 elems): qkvT @0 (3M), woT @3M (1M), w1T @4M (4M),
// w2T @8M (4M); slab total 12M elems = 24MB. 3072 tiles per layer.
#define SLABE 12582912L
__global__ __launch_bounds__(256) void wtransall_kernel(
    const float* __restrict__ Wq, const float* __restrict__ Wk,
    const float* __restrict__ Wv, const float* __restrict__ Wo,
    const float* __restrict__ W1, const float* __restrict__ W2, int lbase,
    long slabstride, _Float16* __restrict__ wall) {
  __shared__ float tt[64][65];
  const int id = blockIdx.x;
  const int lrel = id / 3072;
  const int l = lbase + lrel;
  int t = id % 3072;
  _Float16* slab = wall + (long)lrel * slabstride;
  const long lo = (long)l * DD * DD;
  const long lof = (long)l * DD * FFF;
  const float* src;
  _Float16* dst;
  int K, N;
  if (t < 1024) {
    const int wsel = t >> 8;
    t &= 255;
    src = (wsel == 0 ? Wq : wsel == 1 ? Wk : wsel == 2 ? Wv : Wo) + lo;
    dst = (wsel < 3) ? (slab + (long)wsel * DD * DD) : (slab + 3L * DD * DD);
    K = DD; N = DD;
  } else if (t < 2048) {
    t -= 1024; src = W1 + lof; dst = slab + 4L * DD * DD; K = DD; N = FFF;
  } else {
    t -= 2048; src = W2 + lof; dst = slab + 8L * DD * DD; K = FFF; N = DD;
  }
  const int ntile = N >> 6;
  const int n0 = (t % ntile) << 6;
  const int k0 = (t / ntile) << 6;
  const int tx = threadIdx.x & 63;
  const int ty = threadIdx.x >> 6;
#pragma unroll
  for (int i = 0; i < 16; ++i)
    tt[i * 4 + ty][tx] = src[(long)(k0 + i * 4 + ty) * N + n0 + tx];
  __syncthreads();
#pragma unroll
  for (int i = 0; i < 16; ++i) {
    const int r = i * 4 + ty;
    dst[(long)(n0 + r) * K + k0 + tx] = (_Float16)tt[tx][r];
  }
}

// W [K][N] f32 -> WT [N][K] f16 (Wout)
__global__ __launch_bounds__(256) void wtrans_kernel(
    const float* __restrict__ W, _Float16* __restrict__ WT, int K, int N) {
  __shared__ float tt[64][65];
  const int n0 = blockIdx.x * 64, k0 = blockIdx.y * 64;
  const int tx = threadIdx.x & 63;
  const int ty = threadIdx.x >> 6;
#pragma unroll
  for (int i = 0; i < 16; ++i)
    tt[i * 4 + ty][tx] = W[(long)(k0 + i * 4 + ty) * N + n0 + tx];
  __syncthreads();
#pragma unroll
  for (int i = 0; i < 16; ++i) {
    const int r = i * 4 + ty;
    WT[(long)(n0 + r) * K + k0 + tx] = (_Float16)tt[tx][r];
  }
}

// pack per-layer qkv biases: bqkv[l][3072]
__global__ __launch_bounds__(256) void packb_kernel(
    const float* __restrict__ bq, const float* __restrict__ bk,
    const float* __restrict__ bv, float* __restrict__ bqkv) {
  const int i = blockIdx.x * 256 + threadIdx.x;
  const int l = i / (3 * DD), j = i % (3 * DD);
  float v;
  if (j < DD) v = bq[l * DD + j];
  else if (j < 2 * DD) v = bk[l * DD + j - DD];
  else v = bv[l * DD + j - 2 * DD];
  bqkv[i] = v;
}

// ---------------------------------------------------------------------------
extern "C" void kernel_launch(void* const* d_in, const int* in_sizes, int n_in,
                              void* d_out, int out_size, void* d_ws,
                              size_t ws_size, hipStream_t stream) {
  const int* ids = (const int*)d_in[0];
  const int* amask = (const int*)d_in[1];
  const int* curp = (const int*)d_in[2];
  const float* tok = (const float*)d_in[3];
  const float* pose = (const float*)d_in[4];
  const float* ln1s = (const float*)d_in[5];
  const float* ln1b = (const float*)d_in[6];
  const float* Wq = (const float*)d_in[7];
  const float* bq = (const float*)d_in[8];
  const float* Wk = (const float*)d_in[9];
  const float* bk = (const float*)d_in[10];
  const float* Wv = (const float*)d_in[11];
  const float* bv = (const float*)d_in[12];
  const float* Wo = (const float*)d_in[13];
  const float* bo = (const float*)d_in[14];
  const float* ln2s = (const float*)d_in[15];
  const float* ln2b = (const float*)d_in[16];
  const float* W1 = (const float*)d_in[17];
  const float* b1 = (const float*)d_in[18];
  const float* W2 = (const float*)d_in[19];
  const float* b2 = (const float*)d_in[20];
  const float* lnfs = (const float*)d_in[21];
  const float* lnfb = (const float*)d_in[22];
  const float* Wout = (const float*)d_in[23];
  const float* bout = (const float*)d_in[24];

  const long MSZ = (long)BB * SS * DD;  // 4M elements
  char* wsp = (char*)d_ws;
  float* h = (float*)wsp;                              // 16MB f32
  _Float16* x = (_Float16*)(wsp + 16u * 1024 * 1024);  // 8MB
  _Float16* q = x + MSZ;    // 8MB (q, k, vT contiguous: qkv scatter target)
  _Float16* kb = q + MSZ;   // 8MB
  _Float16* vt = kb + MSZ;  // 8MB [B*H][HD][S]
  _Float16* big = vt + MSZ; // 32MB (MLP mid)
  _Float16* parts = big + MSZ * 4;                  // 32MB (4 f16 partials)
  float* bqkv = (float*)(parts + MSZ * 4);          // 72KB
  _Float16* wall = (_Float16*)((char*)bqkv + 128 * 1024);
  const size_t base_b = (size_t)((char*)wall - wsp);
  const bool prepack =
      ws_size >= base_b + (size_t)(6 * SLABE + (long)DD * DD) * 2 + 4096;
  const int nslab = prepack ? 6 : 1;
  _Float16* woutT = wall + (long)nslab * SLABE;

  const int M = BB * SS;  // 4096
  dim3 blk(256);
  const long pzs = (long)M * DD;

  embed_ln_kernel<<<M, blk, 0, stream>>>(ids, curp, tok, pose, ln1s, ln1b, h, x);
  packb_kernel<<<(LL * 3 * DD) / 256, blk, 0, stream>>>(bq, bk, bv, bqkv);
  wtrans_kernel<<<dim3(DD / 64, DD / 64), blk, 0, stream>>>(Wout, woutT, DD, DD);
  if (prepack)
    wtransall_kernel<<<6 * 3072, blk, 0, stream>>>(Wq, Wk, Wv, Wo, W1, W2, 0,
                                                   SLABE, wall);

  const dim3 gQKV(3 * DD / 128, M / 128, 1);    // (24,32)   768 blocks
  const dim3 gFA(SS / 128, BB * HH);            // (4,64)    256 blocks x 512t
  const dim3 gF1(FFF / 128, M / 128, 1);        // (32,32)   1024
  const dim3 gK2(DD / 128, M / 128, 2);         // (8,32,2)  512  split-K2
  const dim3 gK3(DD / 128, M / 128, 3);         // (8,32,3)  768  split-K3

  for (int l = 0; l < LL; ++l) {
    _Float16* slab = wall + (long)(prepack ? l : 0) * SLABE;
    _Float16* qkvT = slab;
    _Float16* woT = slab + 3L * DD * DD;
    _Float16* w1T = slab + 4L * DD * DD;
    _Float16* w2T = slab + 8L * DD * DD;
    if (!prepack)
      wtransall_kernel<<<3072, blk, 0, stream>>>(Wq, Wk, Wv, Wo, W1, W2, l, 0,
                                                 wall);
    // QKV: [4096,3072] K=1024
    gemmk_kernel<<<gQKV, blk, 0, stream>>>(x, qkvT, bqkv + l * 3 * DD, q,
                                           3 * DD, DD, DD, 0, 0, 0, 1, 0, -1);
    // fused flash attention -> x [B,S,D] f16 (8 waves x 16q)
    flash_kernel<<<gFA, dim3(512), 0, stream>>>(q, kb, vt, amask, x);
    // Wo: split-K2 -> partials; reduce + residual + ln2 -> h, x
    gemmk_kernel<<<gK2, blk, 0, stream>>>(x, woT, nullptr, parts, DD, DD / 2,
                                          DD, DD / 2, DD / 2, pzs, 6, 0, -1);
    reduce_ln_kernel<<<M, blk, 0, stream>>>(parts, 2, h, bo + l * DD,
                                            ln2s + l * DD, ln2b + l * DD, h, x,
                                            pzs);
    // MLP up + GELU: [4096,4096] K=1024
    gemmk_kernel<<<gF1, blk, 0, stream>>>(x, w1T, b1 + l * FFF, big, FFF, DD,
                                          DD, 0, 0, 0, 5, 0, -1);
    // MLP down: split-K3 (768 blocks = one full pass @3/CU).
    // z chunks: 1344 / 1344 / 1408 (ktail64=1 on z=2).
    gemmk_kernel<<<gK3, blk, 0, stream>>>(big, w2T, nullptr, parts, DD, 1344,
                                          FFF, 1344, 1344, pzs, 6, 1, 2);
    const float* ng = (l < LL - 1) ? (ln1s + (l + 1) * DD) : lnfs;
    const float* nb = (l < LL - 1) ? (ln1b + (l + 1) * DD) : lnfb;
    reduce_ln_kernel<<<M, blk, 0, stream>>>(parts, 3, h, b2 + l * DD, ng, nb,
                                            h, x, pzs);
  }
  // final: x @ Wout + bout -> d_out (split-K2, reduce without LN)
  gemmk_kernel<<<gK2, blk, 0, stream>>>(x, woutT, nullptr, parts, DD, DD / 2,
                                        DD, DD / 2, DD / 2, pzs, 6, 0, -1);
  reduce_ln_kernel<<<M, blk, 0, stream>>>(parts, 2, nullptr, bout, nullptr,
                                          nullptr, (float*)d_out, nullptr, pzs);
}

// Round 16
// 1579.664 us; speedup vs baseline: 1.0855x; 1.0855x over previous
//
#include <hip/hip_runtime.h>
#include <hip/hip_bf16.h>
#include <math.h>

#define BB 8
#define SS 512
#define DD 1024
#define LL 6
#define HH 8
#define HDD 128
#define FFF 4096
#define EPSF 1e-5f
#define SCALEF 0.08838834764831845f  // 1/sqrt(128)

typedef __attribute__((ext_vector_type(8))) _Float16 f16x8;
typedef __attribute__((ext_vector_type(4))) _Float16 f16x4;
typedef __attribute__((ext_vector_type(4))) float f32x4;

__device__ __forceinline__ void gload16(const void* g, void* l) {
  __builtin_amdgcn_global_load_lds(
      (const __attribute__((address_space(1))) void*)g,
      (__attribute__((address_space(3))) void*)l, 16, 0, 0);
}

// ===========================================================================
// gemmk: m97 structure, R11/R14-proven config (UNCHANGED from R14).
// 128x128 tile, BK=64, 4 waves, single 32KB LDS buffer, swizzle ^((r&7)<<4)
// both-sides (0 conflicts). ktail64/nzlast: last split-K chunk may run
// ktail64 extra 64-steps (K3 split of FFF: 1344/1344/1408).
// emode: 1 fused-qkv scatter (+bias, V transposed) | 5 gelu+bias f16 |
//        6 f16 split-K partial
// ===========================================================================
__global__ __launch_bounds__(256, 3) void gemmk_kernel(
    const _Float16* __restrict__ Ag, const _Float16* __restrict__ Bg,
    const float* __restrict__ bias, void* __restrict__ outp,
    int Ndim, int Kdim, int Kstr, long zsA, long zsB, long zsOut, int emode,
    int ktail64, int nzlast) {
  __shared__ _Float16 lA[8192];  // 16KB: 128 rows x 64 halves (128B rows)
  __shared__ _Float16 lB[8192];
  const int tid = threadIdx.x;
  const int lane = tid & 63;
  const int wid = tid >> 6;
  const int z = blockIdx.z;
  const int m0 = blockIdx.y * 128;
  const int n0 = blockIdx.x * 128;
  const long K2 = (long)Kstr * 2;
  const char* Azc = (const char*)(Ag + (long)z * zsA + (long)m0 * Kstr);
  const char* Bzc = (const char*)(Bg + (long)z * zsB + (long)n0 * Kstr);

  const int wm = (wid >> 1) * 64;
  const int wn = (wid & 1) * 64;
  const int r16 = lane & 15;
  const int kq = lane >> 4;  // 16B slot 0..3

  long roff[4];  // shared A/B staging geometry: row r, swizzled col sc
#pragma unroll
  for (int i = 0; i < 4; ++i) {
    const int idx = tid + i * 256;
    const int r = idx >> 3;
    const int sc = ((idx & 7) << 4) ^ ((r & 7) << 4);
    roff[i] = (long)r * K2 + sc;
  }

  f32x4 acc[4][4];
#pragma unroll
  for (int mi = 0; mi < 4; ++mi)
#pragma unroll
    for (int ni = 0; ni < 4; ++ni) acc[mi][ni] = (f32x4){0.f, 0.f, 0.f, 0.f};

  const int nt = (Kdim >> 6) + ((z == nzlast) ? ktail64 : 0);
  for (int t = 0; t < nt; ++t) {
    const int kb = t << 7;  // 128B per K-step
    __syncthreads();
#pragma unroll
    for (int i = 0; i < 4; ++i) {
      gload16(Azc + roff[i] + kb, (char*)lA + tid * 16 + i * 4096);
      gload16(Bzc + roff[i] + kb, (char*)lB + tid * 16 + i * 4096);
    }
    __syncthreads();
#pragma unroll
    for (int kk = 0; kk < 2; ++kk) {
      f16x8 af[4], bf[4];
#pragma unroll
      for (int mi = 0; mi < 4; ++mi) {
        const int R = wm + mi * 16 + r16;
        af[mi] = *(const f16x8*)((const char*)lA + R * 128 +
                                 ((kk * 64 + kq * 16) ^ ((R & 7) << 4)));
      }
#pragma unroll
      for (int ni = 0; ni < 4; ++ni) {
        const int R = wn + ni * 16 + r16;
        bf[ni] = *(const f16x8*)((const char*)lB + R * 128 +
                                 ((kk * 64 + kq * 16) ^ ((R & 7) << 4)));
      }
#pragma unroll
      for (int mi = 0; mi < 4; ++mi)
#pragma unroll
        for (int ni = 0; ni < 4; ++ni)
          acc[mi][ni] = __builtin_amdgcn_mfma_f32_16x16x32_f16(
              af[mi], bf[ni], acc[mi][ni], 0, 0, 0);
    }
  }

  _Float16* outH = (_Float16*)outp + (long)z * zsOut;
  const int rj = (lane >> 4) << 2;
  const long MSZq = (long)BB * SS * DD;
#pragma unroll
  for (int mi = 0; mi < 4; ++mi) {
#pragma unroll
    for (int ni = 0; ni < 4; ++ni) {
      const int col = n0 + wn + ni * 16 + r16;
#pragma unroll
      for (int j = 0; j < 4; ++j) {
        const int row = m0 + wm + mi * 16 + rj + j;
        float vv = acc[mi][ni][j];
        if (emode == 1) {  // fused qkv scatter; V written transposed
          vv += bias[col];
          int wsel = col >> 10, c = col & 1023;
          int b_ = row >> 9, s_ = row & 511;
          int hh = c >> 7, hd_ = c & 127;
          if (wsel < 2) {
            outH[wsel * MSZq + (((long)(b_ * HH + hh)) * SS + s_) * HDD + hd_] =
                (_Float16)vv;
          } else {  // V -> [B*H][HD][S]
            outH[2 * MSZq + (((long)(b_ * HH + hh)) * HDD + hd_) * SS + s_] =
                (_Float16)vv;
          }
        } else if (emode == 5) {  // exact GELU(bias+acc), f16
          vv += bias[col];
          vv = 0.5f * vv * (1.0f + erff(vv * 0.70710678118654752f));
          outH[(long)row * Ndim + col] = (_Float16)vv;
        } else {  // 6: f16 split-K partial
          outH[(long)row * Ndim + col] = (_Float16)vv;
        }
      }
    }
  }
}

// ===========================================================================
// flash (R14-proven EXACT: 4 waves x 32q per 128-q block; wave redundancy
// lesson from R10/R15: K/V re-read scales with waves/block -> keep 4).
// ===========================================================================
__global__ __launch_bounds__(256) void flash_kernel(
    const _Float16* __restrict__ Qg, const _Float16* __restrict__ Kg,
    const _Float16* __restrict__ Vt, const int* __restrict__ amask,
    _Float16* __restrict__ xout) {
  __shared__ _Float16 Pl[4][32][136];
  __shared__ float rf_s[4][32];
  const int tid = threadIdx.x;
  const int lane = tid & 63;
  const int w = tid >> 6;
  const int bh = blockIdx.y;
  const int b_ = bh >> 3, hh = bh & 7;
  const int q0 = blockIdx.x * 128 + w * 32;
  const int r16 = lane & 15;
  const int kq = lane >> 4;
  const int rj = kq << 2;
  const _Float16* Qb = Qg + ((long)bh * SS + q0) * HDD;
  const _Float16* Kb = Kg + (long)bh * SS * HDD;
  const _Float16* Vb = Vt + (long)bh * HDD * SS;

  f16x8 qa[2][4];
#pragma unroll
  for (int mi = 0; mi < 2; ++mi)
#pragma unroll
    for (int kk = 0; kk < 4; ++kk)
      qa[mi][kk] = *(const f16x8*)(Qb + (long)(mi * 16 + r16) * HDD + kk * 32 +
                                   kq * 8);

  f32x4 acc[8][2];  // out^T: [hd 8x16][q 2x16]
#pragma unroll
  for (int mi = 0; mi < 8; ++mi)
#pragma unroll
    for (int ni = 0; ni < 2; ++ni) acc[mi][ni] = (f32x4){0.f, 0.f, 0.f, 0.f};
  float mrun[2][4], lrun[2][4];
#pragma unroll
  for (int mi = 0; mi < 2; ++mi)
#pragma unroll
    for (int j = 0; j < 4; ++j) {
      mrun[mi][j] = -INFINITY;
      lrun[mi][j] = 0.f;
    }

  for (int kt = 0; kt < 4; ++kt) {
    __syncthreads();  // protect Pl/rf_s reuse across iterations
    const int s0 = kt * 128;
    int am[8];
#pragma unroll
    for (int ni = 0; ni < 8; ++ni)
      am[ni] = amask[b_ * SS + s0 + ni * 16 + r16];

    f32x4 sc[2][8];
#pragma unroll
    for (int mi = 0; mi < 2; ++mi)
#pragma unroll
      for (int ni = 0; ni < 8; ++ni) sc[mi][ni] = (f32x4){0.f, 0.f, 0.f, 0.f};
#pragma unroll
    for (int ni = 0; ni < 8; ++ni) {
      f16x8 kf[4];
#pragma unroll
      for (int kk = 0; kk < 4; ++kk)
        kf[kk] = *(const f16x8*)(Kb + (long)(s0 + ni * 16 + r16) * HDD +
                                 kk * 32 + kq * 8);
#pragma unroll
      for (int mi = 0; mi < 2; ++mi)
#pragma unroll
        for (int kk = 0; kk < 4; ++kk)
          sc[mi][ni] = __builtin_amdgcn_mfma_f32_16x16x32_f16(
              qa[mi][kk], kf[kk], sc[mi][ni], 0, 0, 0);
    }
#pragma unroll
    for (int mi = 0; mi < 2; ++mi)
#pragma unroll
      for (int ni = 0; ni < 8; ++ni)
#pragma unroll
        for (int j = 0; j < 4; ++j)
          sc[mi][ni][j] = am[ni] ? sc[mi][ni][j] * SCALEF : -10000.0f;

    float rf[2][4];
#pragma unroll
    for (int mi = 0; mi < 2; ++mi)
#pragma unroll
      for (int j = 0; j < 4; ++j) {
        float rm = -INFINITY;
#pragma unroll
        for (int ni = 0; ni < 8; ++ni) rm = fmaxf(rm, sc[mi][ni][j]);
#pragma unroll
        for (int off = 1; off < 16; off <<= 1)
          rm = fmaxf(rm, __shfl_xor(rm, off));
        const float mn = fmaxf(mrun[mi][j], rm);
        const float rfv = __expf(mrun[mi][j] - mn);
        mrun[mi][j] = mn;
        float rs = 0.f;
#pragma unroll
        for (int ni = 0; ni < 8; ++ni) {
          const float p = __expf(sc[mi][ni][j] - mn);
          sc[mi][ni][j] = p;
          rs += p;
        }
#pragma unroll
        for (int off = 1; off < 16; off <<= 1) rs += __shfl_xor(rs, off);
        lrun[mi][j] = lrun[mi][j] * rfv + rs;
        rf[mi][j] = rfv;
      }
    if (r16 == 0) {
#pragma unroll
      for (int mi = 0; mi < 2; ++mi)
#pragma unroll
        for (int j = 0; j < 4; ++j) rf_s[w][mi * 16 + rj + j] = rf[mi][j];
    }
#pragma unroll
    for (int mi = 0; mi < 2; ++mi)
#pragma unroll
      for (int ni = 0; ni < 8; ++ni)
#pragma unroll
        for (int j = 0; j < 4; ++j)
          Pl[w][mi * 16 + rj + j][ni * 16 + r16] = (_Float16)sc[mi][ni][j];
    __syncthreads();

    float rfq[2];
    rfq[0] = rf_s[w][r16];
    rfq[1] = rf_s[w][16 + r16];
#pragma unroll
    for (int mi2 = 0; mi2 < 8; ++mi2)
#pragma unroll
      for (int ni2 = 0; ni2 < 2; ++ni2)
#pragma unroll
        for (int j = 0; j < 4; ++j) acc[mi2][ni2][j] *= rfq[ni2];

    f16x8 pb[2][4];
#pragma unroll
    for (int ni2 = 0; ni2 < 2; ++ni2)
#pragma unroll
      for (int kk = 0; kk < 4; ++kk)
        pb[ni2][kk] =
            *(const f16x8*)(&Pl[w][ni2 * 16 + r16][kk * 32 + kq * 8]);
#pragma unroll
    for (int mi2 = 0; mi2 < 8; ++mi2) {
      f16x8 va[4];
#pragma unroll
      for (int kk = 0; kk < 4; ++kk)
        va[kk] = *(const f16x8*)(Vb + (long)(mi2 * 16 + r16) * SS + s0 +
                                 kk * 32 + kq * 8);
#pragma unroll
      for (int ni2 = 0; ni2 < 2; ++ni2)
#pragma unroll
        for (int kk = 0; kk < 4; ++kk)
          acc[mi2][ni2] = __builtin_amdgcn_mfma_f32_16x16x32_f16(
              va[kk], pb[ni2][kk], acc[mi2][ni2], 0, 0, 0);
    }
  }

  __syncthreads();
  if (r16 == 0) {
#pragma unroll
    for (int mi = 0; mi < 2; ++mi)
#pragma unroll
      for (int j = 0; j < 4; ++j)
        rf_s[w][mi * 16 + rj + j] = 1.0f / lrun[mi][j];
  }
  __syncthreads();
  float lq[2];
  lq[0] = rf_s[w][r16];
  lq[1] = rf_s[w][16 + r16];
#pragma unroll
  for (int mi2 = 0; mi2 < 8; ++mi2)
#pragma unroll
    for (int ni2 = 0; ni2 < 2; ++ni2) {
      f16x4 o;
#pragma unroll
      for (int j = 0; j < 4; ++j) o[j] = (_Float16)(acc[mi2][ni2][j] * lq[ni2]);
      const int qg = q0 + ni2 * 16 + r16;
      *(f16x4*)(&xout[((long)(b_ * SS + qg)) * DD + hh * HDD + mi2 * 16 + rj]) =
          o;
    }
}

// ===========================================================================
// reduce_ln: h[row] = (res?res:0) + bias + sum parts; optional LN -> x (f16)
// ===========================================================================
__global__ __launch_bounds__(256) void reduce_ln_kernel(
    const _Float16* __restrict__ parts, int npart,
    const float* __restrict__ res, const float* __restrict__ bias,
    const float* __restrict__ lg, const float* __restrict__ lb,
    float* __restrict__ hout, _Float16* __restrict__ xout, long pzs) {
  const int row = blockIdx.x;
  const int c = threadIdx.x << 2;
  const long base = (long)row * DD + c;
  float4 a = *reinterpret_cast<const float4*>(&bias[c]);
  if (res) {
    const float4 r = *reinterpret_cast<const float4*>(&res[base]);
    a.x += r.x; a.y += r.y; a.z += r.z; a.w += r.w;
  }
  for (int p = 0; p < npart; ++p) {
    const f16x4 hpv = *reinterpret_cast<const f16x4*>(&parts[p * pzs + base]);
    a.x += (float)hpv[0]; a.y += (float)hpv[1];
    a.z += (float)hpv[2]; a.w += (float)hpv[3];
  }
  *reinterpret_cast<float4*>(&hout[base]) = a;
  if (!lg) return;
  float s = a.x + a.y + a.z + a.w;
  float ss = a.x * a.x + a.y * a.y + a.z * a.z + a.w * a.w;
#pragma unroll
  for (int off = 32; off; off >>= 1) {
    s += __shfl_down(s, off);
    ss += __shfl_down(ss, off);
  }
  __shared__ float red[8];
  const int wid = threadIdx.x >> 6, lane = threadIdx.x & 63;
  if (lane == 0) { red[wid] = s; red[4 + wid] = ss; }
  __syncthreads();
  if (threadIdx.x == 0) {
    s = red[0] + red[1] + red[2] + red[3];
    ss = red[4] + red[5] + red[6] + red[7];
    float mean = s * (1.0f / DD);
    float var = ss * (1.0f / DD) - mean * mean;
    red[0] = mean;
    red[1] = rsqrtf(var + EPSF);
  }
  __syncthreads();
  const float mean = red[0], rstd = red[1];
  const float4 gv = *reinterpret_cast<const float4*>(&lg[c]);
  const float4 bv = *reinterpret_cast<const float4*>(&lb[c]);
  f16x4 o;
  o[0] = (_Float16)((a.x - mean) * rstd * gv.x + bv.x);
  o[1] = (_Float16)((a.y - mean) * rstd * gv.y + bv.y);
  o[2] = (_Float16)((a.z - mean) * rstd * gv.z + bv.z);
  o[3] = (_Float16)((a.w - mean) * rstd * gv.w + bv.w);
  *reinterpret_cast<f16x4*>(&xout[base]) = o;
}

// embed + layer-0 ln1 fused
__global__ __launch_bounds__(256) void embed_ln_kernel(
    const int* __restrict__ ids, const int* __restrict__ curpos,
    const float* __restrict__ tok, const float* __restrict__ pos,
    const float* __restrict__ lg, const float* __restrict__ lb,
    float* __restrict__ h, _Float16* __restrict__ x) {
  const int rs = blockIdx.x;
  const int s_ = rs & (SS - 1);
  const int t = ids[rs];
  const int p = curpos[0] + s_;
  const int c = threadIdx.x << 2;
  const float4 tv = *reinterpret_cast<const float4*>(&tok[(long)t * DD + c]);
  const float4 pv = *reinterpret_cast<const float4*>(&pos[(long)p * DD + c]);
  float4 a = {tv.x + pv.x, tv.y + pv.y, tv.z + pv.z, tv.w + pv.w};
  *reinterpret_cast<float4*>(&h[(long)rs * DD + c]) = a;
  float s = a.x + a.y + a.z + a.w;
  float ss = a.x * a.x + a.y * a.y + a.z * a.z + a.w * a.w;
#pragma unroll
  for (int off = 32; off; off >>= 1) {
    s += __shfl_down(s, off);
    ss += __shfl_down(ss, off);
  }
  __shared__ float red[8];
  const int wid = threadIdx.x >> 6, lane = threadIdx.x & 63;
  if (lane == 0) { red[wid] = s; red[4 + wid] = ss; }
  __syncthreads();
  if (threadIdx.x == 0) {
    s = red[0] + red[1] + red[2] + red[3];
    ss = red[4] + red[5] + red[6] + red[7];
    float mean = s * (1.0f / DD);
    float var = ss * (1.0f / DD) - mean * mean;
    red[0] = mean;
    red[1] = rsqrtf(var + EPSF);
  }
  __syncthreads();
  const float mean = red[0], rstd = red[1];
  const float4 gv = *reinterpret_cast<const float4*>(&lg[c]);
  const float4 bv = *reinterpret_cast<const float4*>(&lb[c]);
  f16x4 o;
  o[0] = (_Float16)((a.x - mean) * rstd * gv.x + bv.x);
  o[1] = (_Float16)((a.y - mean) * rstd * gv.y + bv.y);
  o[2] = (_Float16)((a.z - mean) * rstd * gv.z + bv.z);
  o[3] = (_Float16)((a.w - mean) * rstd * gv.w + bv.w);
  *reinterpret_cast<f16x4*>(&x[(long)rs * DD + c]) = o;
}

// per-layer slab (f16 elems): qkvT @0 (3M), woT @3M (1M), w1T @4M (4M),
// w2T @8M (4M); slab 12M elems = 24MB; 3072 tiles/layer. Blocks beyond
// 6*3072 handle the Wout transpose (256 tiles) -> woutT.
#define SLABE 12582912L
__global__ __launch_bounds__(256) void wtransall_kernel(
    const float* __restrict__ Wq, const float* __restrict__ Wk,
    const float* __restrict__ Wv, const float* __restrict__ Wo,
    const float* __restrict__ W1, const float* __restrict__ W2,
    const float* __restrict__ WoutG, int lbase, long slabstride,
    _Float16* __restrict__ wall, _Float16* __restrict__ woutT) {
  __shared__ float tt[64][65];
  const int id = blockIdx.x;
  const float* src;
  _Float16* dst;
  int K, N, t;
  if (woutT && id >= 6 * 3072) {  // Wout tile
    t = id - 6 * 3072;
    src = WoutG;
    dst = woutT;
    K = DD; N = DD;
  } else {
    const int lrel = id / 3072;
    const int l = lbase + lrel;
    t = id % 3072;
    _Float16* slab = wall + (long)lrel * slabstride;
    const long lo = (long)l * DD * DD;
    const long lof = (long)l * DD * FFF;
    if (t < 1024) {
      const int wsel = t >> 8;
      t &= 255;
      src = (wsel == 0 ? Wq : wsel == 1 ? Wk : wsel == 2 ? Wv : Wo) + lo;
      dst = (wsel < 3) ? (slab + (long)wsel * DD * DD) : (slab + 3L * DD * DD);
      K = DD; N = DD;
    } else if (t < 2048) {
      t -= 1024; src = W1 + lof; dst = slab + 4L * DD * DD; K = DD; N = FFF;
    } else {
      t -= 2048; src = W2 + lof; dst = slab + 8L * DD * DD; K = FFF; N = DD;
    }
  }
  const int ntile = N >> 6;
  const int n0 = (t % ntile) << 6;
  const int k0 = (t / ntile) << 6;
  const int tx = threadIdx.x & 63;
  const int ty = threadIdx.x >> 6;
#pragma unroll
  for (int i = 0; i < 16; ++i)
    tt[i * 4 + ty][tx] = src[(long)(k0 + i * 4 + ty) * N + n0 + tx];
  __syncthreads();
#pragma unroll
  for (int i = 0; i < 16; ++i) {
    const int r = i * 4 + ty;
    dst[(long)(n0 + r) * K + k0 + tx] = (_Float16)tt[tx][r];
  }
}

// W [K][N] f32 -> WT [N][K] f16 (non-prepack fallback for Wout)
__global__ __launch_bounds__(256) void wtrans_kernel(
    const float* __restrict__ W, _Float16* __restrict__ WT, int K, int N) {
  __shared__ float tt[64][65];
  const int n0 = blockIdx.x * 64, k0 = blockIdx.y * 64;
  const int tx = threadIdx.x & 63;
  const int ty = threadIdx.x >> 6;
#pragma unroll
  for (int i = 0; i < 16; ++i)
    tt[i * 4 + ty][tx] = W[(long)(k0 + i * 4 + ty) * N + n0 + tx];
  __syncthreads();
#pragma unroll
  for (int i = 0; i < 16; ++i) {
    const int r = i * 4 + ty;
    WT[(long)(n0 + r) * K + k0 + tx] = (_Float16)tt[tx][r];
  }
}

// pack per-layer qkv biases: bqkv[l][3072]
__global__ __launch_bounds__(256) void packb_kernel(
    const float* __restrict__ bq, const float* __restrict__ bk,
    const float* __restrict__ bv, float* __restrict__ bqkv) {
  const int i = blockIdx.x * 256 + threadIdx.x;
  const int l = i / (3 * DD), j = i % (3 * DD);
  float v;
  if (j < DD) v = bq[l * DD + j];
  else if (j < 2 * DD) v = bk[l * DD + j - DD];
  else v = bv[l * DD + j - 2 * DD];
  bqkv[i] = v;
}

// ---------------------------------------------------------------------------
extern "C" void kernel_launch(void* const* d_in, const int* in_sizes, int n_in,
                              void* d_out, int out_size, void* d_ws,
                              size_t ws_size, hipStream_t stream) {
  const int* ids = (const int*)d_in[0];
  const int* amask = (const int*)d_in[1];
  const int* curp = (const int*)d_in[2];
  const float* tok = (const float*)d_in[3];
  const float* pose = (const float*)d_in[4];
  const float* ln1s = (const float*)d_in[5];
  const float* ln1b = (const float*)d_in[6];
  const float* Wq = (const float*)d_in[7];
  const float* bq = (const float*)d_in[8];
  const float* Wk = (const float*)d_in[9];
  const float* bk = (const float*)d_in[10];
  const float* Wv = (const float*)d_in[11];
  const float* bv = (const float*)d_in[12];
  const float* Wo = (const float*)d_in[13];
  const float* bo = (const float*)d_in[14];
  const float* ln2s = (const float*)d_in[15];
  const float* ln2b = (const float*)d_in[16];
  const float* W1 = (const float*)d_in[17];
  const float* b1 = (const float*)d_in[18];
  const float* W2 = (const float*)d_in[19];
  const float* b2 = (const float*)d_in[20];
  const float* lnfs = (const float*)d_in[21];
  const float* lnfb = (const float*)d_in[22];
  const float* Wout = (const float*)d_in[23];
  const float* bout = (const float*)d_in[24];

  const long MSZ = (long)BB * SS * DD;  // 4M elements
  char* wsp = (char*)d_ws;
  float* h = (float*)wsp;                              // 16MB f32
  _Float16* x = (_Float16*)(wsp + 16u * 1024 * 1024);  // 8MB
  _Float16* q = x + MSZ;    // 8MB (q, k, vT contiguous: qkv scatter target)
  _Float16* kb = q + MSZ;   // 8MB
  _Float16* vt = kb + MSZ;  // 8MB [B*H][HD][S]
  _Float16* big = vt + MSZ; // 32MB (MLP mid)
  _Float16* parts = big + MSZ * 4;                  // 32MB (4 f16 partials)
  float* bqkv = (float*)(parts + MSZ * 4);          // 72KB
  _Float16* wall = (_Float16*)((char*)bqkv + 128 * 1024);
  const size_t base_b = (size_t)((char*)wall - wsp);
  const bool prepack =
      ws_size >= base_b + (size_t)(6 * SLABE + (long)DD * DD) * 2 + 4096;
  const int nslab = prepack ? 6 : 1;
  _Float16* woutT = wall + (long)nslab * SLABE;

  const int M = BB * SS;  // 4096
  dim3 blk(256);
  const long pzs = (long)M * DD;

  embed_ln_kernel<<<M, blk, 0, stream>>>(ids, curp, tok, pose, ln1s, ln1b, h, x);
  packb_kernel<<<(LL * 3 * DD) / 256, blk, 0, stream>>>(bq, bk, bv, bqkv);
  if (prepack) {
    wtransall_kernel<<<6 * 3072 + 256, blk, 0, stream>>>(
        Wq, Wk, Wv, Wo, W1, W2, Wout, 0, SLABE, wall, woutT);
  } else {
    wtrans_kernel<<<dim3(DD / 64, DD / 64), blk, 0, stream>>>(Wout, woutT, DD,
                                                              DD);
  }

  const dim3 gQKV(3 * DD / 128, M / 128, 1);    // (24,32)   768 blocks
  const dim3 gFA(SS / 128, BB * HH);            // (4,64)    256
  const dim3 gF1(FFF / 128, M / 128, 1);        // (32,32)   1024
  const dim3 gK2(DD / 128, M / 128, 2);         // (8,32,2)  512  split-K2
  const dim3 gK3(DD / 128, M / 128, 3);         // (8,32,3)  768  split-K3

  for (int l = 0; l < LL; ++l) {
    _Float16* slab = wall + (long)(prepack ? l : 0) * SLABE;
    _Float16* qkvT = slab;
    _Float16* woT = slab + 3L * DD * DD;
    _Float16* w1T = slab + 4L * DD * DD;
    _Float16* w2T = slab + 8L * DD * DD;
    if (!prepack)
      wtransall_kernel<<<3072, blk, 0, stream>>>(Wq, Wk, Wv, Wo, W1, W2,
                                                 nullptr, l, 0, wall, nullptr);
    // QKV: [4096,3072] K=1024
    gemmk_kernel<<<gQKV, blk, 0, stream>>>(x, qkvT, bqkv + l * 3 * DD, q,
                                           3 * DD, DD, DD, 0, 0, 0, 1, 0, -1);
    // fused flash attention -> x [B,S,D] f16
    flash_kernel<<<gFA, blk, 0, stream>>>(q, kb, vt, amask, x);
    // Wo: split-K2 -> partials; reduce + residual + ln2 -> h, x
    gemmk_kernel<<<gK2, blk, 0, stream>>>(x, woT, nullptr, parts, DD, DD / 2,
                                          DD, DD / 2, DD / 2, pzs, 6, 0, -1);
    reduce_ln_kernel<<<M, blk, 0, stream>>>(parts, 2, h, bo + l * DD,
                                            ln2s + l * DD, ln2b + l * DD, h, x,
                                            pzs);
    // MLP up + GELU: [4096,4096] K=1024
    gemmk_kernel<<<gF1, blk, 0, stream>>>(x, w1T, b1 + l * FFF, big, FFF, DD,
                                          DD, 0, 0, 0, 5, 0, -1);
    // MLP down: split-K3 (768 blocks = one full pass @3/CU).
    // z chunks: 1344 / 1344 / 1408 (ktail64=1 on z=2).
    gemmk_kernel<<<gK3, blk, 0, stream>>>(big, w2T, nullptr, parts, DD, 1344,
                                          FFF, 1344, 1344, pzs, 6, 1, 2);
    const float* ng = (l < LL - 1) ? (ln1s + (l + 1) * DD) : lnfs;
    const float* nb = (l < LL - 1) ? (ln1b + (l + 1) * DD) : lnfb;
    reduce_ln_kernel<<<M, blk, 0, stream>>>(parts, 3, h, b2 + l * DD, ng, nb,
                                            h, x, pzs);
  }
  // final: x @ Wout + bout -> d_out (split-K2, reduce without LN)
  gemmk_kernel<<<gK2, blk, 0, stream>>>(x, woutT, nullptr, parts, DD, DD / 2,
                                        DD, DD / 2, DD / 2, pzs, 6, 0, -1);
  reduce_ln_kernel<<<M, blk, 0, stream>>>(parts, 2, nullptr, bout, nullptr,
                                          nullptr, (float*)d_out, nullptr, pzs);
}